// Round 2
// baseline (159.564 us; speedup 1.0000x reference)
//
#include <hip/hip_runtime.h>

typedef unsigned short u16;
typedef unsigned int u32;
typedef __attribute__((ext_vector_type(8))) short short8;
typedef __attribute__((ext_vector_type(8))) __bf16 bf16x8;
typedef __attribute__((ext_vector_type(4))) float f32x4;
typedef __attribute__((ext_vector_type(16))) float f32x16;
typedef __attribute__((ext_vector_type(4))) unsigned short us4;
typedef __attribute__((ext_vector_type(4))) unsigned int u32x4;

#define DEVFN static __device__ __forceinline__

DEVFN u16 f2bf(float f) {
  u32 u = __float_as_uint(f);
  return (u16)((u + 0x7fffu + ((u >> 16) & 1u)) >> 16);  // RNE, finite inputs
}

#if __has_builtin(__builtin_amdgcn_exp2f)
DEVFN float fexp2(float x) { return __builtin_amdgcn_exp2f(x); }
#else
DEVFN float fexp2(float x) { return exp2f(x); }
#endif

// ---- MFMA wrappers: tolerant of short8-typed or bf16x8-typed builtins ----
template <typename T>
DEVFN auto mfma16_imp(T a, T b, f32x4 c, int)
    -> decltype(__builtin_amdgcn_mfma_f32_16x16x32_bf16(a, b, c, 0, 0, 0)) {
  return __builtin_amdgcn_mfma_f32_16x16x32_bf16(a, b, c, 0, 0, 0);
}
template <typename T>
DEVFN f32x4 mfma16_imp(T a, T b, f32x4 c, long) {
  return __builtin_amdgcn_mfma_f32_16x16x32_bf16(
      __builtin_bit_cast(bf16x8, a), __builtin_bit_cast(bf16x8, b), c, 0, 0, 0);
}
DEVFN f32x4 MFMA(short8 a, short8 b, f32x4 c) { return mfma16_imp(a, b, c, 0); }

template <typename T>
DEVFN auto mfma32_imp(T a, T b, f32x16 c, int)
    -> decltype(__builtin_amdgcn_mfma_f32_32x32x16_bf16(a, b, c, 0, 0, 0)) {
  return __builtin_amdgcn_mfma_f32_32x32x16_bf16(a, b, c, 0, 0, 0);
}
template <typename T>
DEVFN f32x16 mfma32_imp(T a, T b, f32x16 c, long) {
  return __builtin_amdgcn_mfma_f32_32x32x16_bf16(
      __builtin_bit_cast(bf16x8, a), __builtin_bit_cast(bf16x8, b), c, 0, 0, 0);
}
DEVFN f32x16 MFMA32(short8 a, short8 b, f32x16 c) { return mfma32_imp(a, b, c, 0); }

// ---- async global->LDS: dest = uniform base + lane*16 ----
DEVFN void gload_lds16(const u16* g, u16* l) {
  __builtin_amdgcn_global_load_lds(
      (__attribute__((address_space(1))) void*)g,
      (__attribute__((address_space(3))) void*)l, 16, 0, 0);
}

DEVFN u32 cvtpk_bf16(float lo, float hi) {
  u32 w;
  asm("v_cvt_pk_bf16_f32 %0, %1, %2" : "=v"(w) : "v"(lo), "v"(hi));
  return w;
}

// V scatter-transpose into V^T LDS tile with bank-spread swizzle.
// Layout must match PV read: Vs[d*64 + ((kvhi ^ (d&7) ^ ((d>>3)&7))*8) + kvlo]
// gtid in [0,256): the 256 threads of one kv-group.
DEVFN void vscatter(int gtid, short8 a, short8 b, u16* dst) {
#pragma unroll
  for (int c = 0; c < 2; ++c) {
    short8 vv = c ? b : a;
    int gg = c * 256 + gtid;
    int kv = gg >> 3, d0 = (gg & 7) * 8;
    int kvhi = kv >> 3, kvlo = kv & 7;
#pragma unroll
    for (int i = 0; i < 8; ++i) {
      int d = d0 + i;
      dst[d * 64 + ((kvhi ^ (d & 7) ^ ((d >> 3) & 7)) * 8) + kvlo] = (u16)vv[i];
    }
  }
}

// ================= f32 -> bf16 conversion =================
__global__ void __launch_bounds__(256) cvt_kernel(const float* __restrict__ in,
                                                  u16* __restrict__ out, int n4) {
  int i = blockIdx.x * 256 + threadIdx.x;
  if (i < n4) {
    f32x4 v = ((const f32x4*)in)[i];
    us4 o;
    o[0] = f2bf(v[0]); o[1] = f2bf(v[1]); o[2] = f2bf(v[2]); o[3] = f2bf(v[3]);
    ((us4*)out)[i] = o;
  }
}

// ================= GEMM: C[M,N] = A[M,K] @ B[N,K]^T (bf16 in, fp32 acc) ===
template <int F32OUT>
__global__ void __launch_bounds__(256) gemm_bt(
    const u16* __restrict__ A, const u16* __restrict__ Bm,
    u16* __restrict__ Cbf, float* __restrict__ Cf, const float* __restrict__ bias,
    int M, int N, int K) {
  __shared__ u16 As[128 * 32];
  __shared__ u16 Bs[128 * 32];
  const int tid = threadIdx.x;
  const int wave = tid >> 6, lane = tid & 63;
  const int bm = blockIdx.x * 128, bn = blockIdx.y * 128;
  const int wr = (wave >> 1) * 64, wc = (wave & 1) * 64;
  const int srow = lane >> 2, scol = (lane & 3) * 8;
  const int fr = lane & 15, fk = (lane >> 4) * 8;

  f32x4 acc[4][4] = {};

  for (int k0 = 0; k0 < K; k0 += 32) {
    __syncthreads();
#pragma unroll
    for (int t = 0; t < 2; ++t) {
      int rr = (wave * 2 + t) * 16 + srow;
      gload_lds16(A + (size_t)(bm + rr) * K + k0 + scol, As + (wave * 2 + t) * 512);
      gload_lds16(Bm + (size_t)(bn + rr) * K + k0 + scol, Bs + (wave * 2 + t) * 512);
    }
    __syncthreads();
    short8 af[4], bf[4];
#pragma unroll
    for (int i = 0; i < 4; ++i) {
      af[i] = *(const short8*)(As + (wr + i * 16 + fr) * 32 + fk);
      bf[i] = *(const short8*)(Bs + (wc + i * 16 + fr) * 32 + fk);
    }
#pragma unroll
    for (int mi = 0; mi < 4; ++mi)
#pragma unroll
      for (int ni = 0; ni < 4; ++ni)
        acc[mi][ni] = MFMA(af[mi], bf[ni], acc[mi][ni]);
  }

  const int orow = (lane >> 4) * 4, ocol = lane & 15;
#pragma unroll
  for (int mi = 0; mi < 4; ++mi)
#pragma unroll
    for (int ni = 0; ni < 4; ++ni)
#pragma unroll
      for (int r = 0; r < 4; ++r) {
        size_t row = (size_t)(bm + wr + mi * 16 + orow + r);
        size_t col = (size_t)(bn + wc + ni * 16 + ocol);
        if (F32OUT)
          Cf[row * N + col] = acc[mi][ni][r] + bias[col];
        else
          Cbf[row * N + col] = f2bf(acc[mi][ni][r]);
      }
}

// ================= Flash attention v3: in-block KV-split x2 =================
// qkv: [4096, 3072] bf16. Grid (16 qblk, 16 heads, 2 batch), 512 thr (8 waves).
// Waves 0-3 (group 0) process kv [0,1024); waves 4-7 (group 1) kv [1024,2048)
// for the SAME 128 q-rows. Each group: own double-buffered K/V LDS (32KB),
// swapped-operand 32x32 QK^T, in-register softmax, cvt_pk+permlane P-redist,
// async-issue staging. After the loop: flash-combine of the two partial
// (m,l,O) states through LDS (overlaid on dead K/V buffers).
// Rationale: wave count was grid-capped at 2/SIMD (2048 waves); split doubles
// it to 4/SIMD (96 VGPR allows exactly 16 waves/CU).
__global__ void __launch_bounds__(512, 4) attn_kernel(const u16* __restrict__ qkv,
                                                      u16* __restrict__ attn_out) {
  // 64KB flat: K(g,buf) at (g*2+buf)*4096, V(g,buf) at 16384+(g*2+buf)*4096
  __shared__ u16 SM[32768];

  const int tid = threadIdx.x;
  const int wave = tid >> 6, lane = tid & 63;
  const int g = wave >> 2, gw = wave & 3;   // kv-group, wave-in-group
  const int gtid = tid & 255;               // thread-in-group
  const int q5 = lane & 31, hi = lane >> 5;
  const int qb = blockIdx.x, h = blockIdx.y, b = blockIdx.z;
  const size_t tok0 = (size_t)b * 2048;
  const float SCALE = 0.18033688011112042f;  // 0.125 * log2(e)

  u16* const Kg = SM + g * 2 * 4096;          // + cur*4096
  u16* const Vg = SM + 16384 + g * 2 * 4096;  // + cur*4096
  const int kvbase = g * 1024;

  // Q B-frags: lane q5 holds Q[q][ks*16 + hi*8 + j]
  const size_t qrow = tok0 + qb * 128 + gw * 32 + q5;
  const u16* qp = qkv + qrow * 3072 + h * 64 + hi * 8;
  short8 qf[4];
#pragma unroll
  for (int ks = 0; ks < 4; ++ks) qf[ks] = *(const short8*)(qp + ks * 16);

  const u16* kbase = qkv + tok0 * 3072 + 1024 + h * 64;
  const u16* vbase = qkv + tok0 * 3072 + 2048 + h * 64;

  // K staging src (per lane, static): row_in_8 = lane>>3, src chunk = (lane&7)^(lane>>3)
  const int k_srcoff = (((lane & 7) ^ (lane >> 3)) * 8);
  const int k_rowl = lane >> 3;
  // V load indices (per group-thread, static)
  const int v_kv0 = gtid >> 3, v_d0 = (gtid & 7) * 8;  // c=0
  const int v_kv1 = 32 + (gtid >> 3);                  // c=1 (same d0)

  float m_run = -1e30f, l_run = 0.f;
  f32x16 o0 = {}, o1 = {};

  // ---- prologue: stage this group's tile 0 into buffer 0 ----
#pragma unroll
  for (int c = 0; c < 2; ++c) {
    int row = (c * 4 + gw) * 8 + k_rowl;
    gload_lds16(kbase + (size_t)(kvbase + row) * 3072 + k_srcoff,
                Kg + (c * 4 + gw) * 512);
  }
  {
    short8 va = *(const short8*)(vbase + (size_t)(kvbase + v_kv0) * 3072 + v_d0);
    short8 vb = *(const short8*)(vbase + (size_t)(kvbase + v_kv1) * 3072 + v_d0);
    vscatter(gtid, va, vb, Vg);
  }
  __syncthreads();  // drains vmcnt (K gload_lds) + lgkm (V scatter)

  for (int t = 0; t < 16; ++t) {
    const int cur = t & 1, nxt = cur ^ 1;
    const int kv1 = kvbase + (t + 1) * 64;
    short8 vna = {}, vnb = {};
    if (t < 15) {
      // ---- async-issue next tile: K direct-to-LDS, V to regs ----
#pragma unroll
      for (int c = 0; c < 2; ++c) {
        int row = (c * 4 + gw) * 8 + k_rowl;
        gload_lds16(kbase + (size_t)(kv1 + row) * 3072 + k_srcoff,
                    Kg + nxt * 4096 + (c * 4 + gw) * 512);
      }
      vna = *(const short8*)(vbase + (size_t)(kv1 + v_kv0) * 3072 + v_d0);
      vnb = *(const short8*)(vbase + (size_t)(kv1 + v_kv1) * 3072 + v_d0);
    }

    // ---- S^T = K . Q^T : 2 tiles (kv 0-31 / 32-63), 4 k-steps ----
    const u16* Kc = Kg + cur * 4096;
    f32x16 s0 = {}, s1 = {};
    __builtin_amdgcn_s_setprio(1);
#pragma unroll
    for (int ks = 0; ks < 4; ++ks) {
      int ch = ((ks * 2 + hi) ^ (q5 & 7)) * 8;
      short8 k0 = *(const short8*)(Kc + q5 * 64 + ch);
      short8 k1 = *(const short8*)(Kc + (32 + q5) * 64 + ch);
      s0 = MFMA32(k0, qf[ks], s0);
      s1 = MFMA32(k1, qf[ks], s1);
    }
    __builtin_amdgcn_s_setprio(0);

    // ---- online softmax, per-lane scalars (lane owns q = q5) ----
    float mt[8];
#pragma unroll
    for (int i = 0; i < 8; ++i)
      mt[i] = fmaxf(fmaxf(s0[i], s0[i + 8]), fmaxf(s1[i], s1[i + 8]));
    float pmax = fmaxf(fmaxf(fmaxf(mt[0], mt[1]), fmaxf(mt[2], mt[3])),
                       fmaxf(fmaxf(mt[4], mt[5]), fmaxf(mt[6], mt[7])));
    pmax = fmaxf(pmax, __shfl_xor(pmax, 32, 64));
    float mraw = pmax * SCALE;

    if (__any(mraw > m_run + 8.f)) {  // T13 defer-max, wave-uniform
      float mn = fmaxf(m_run, mraw);
      float alpha = fexp2(m_run - mn);
#pragma unroll
      for (int i = 0; i < 16; ++i) { o0[i] *= alpha; o1[i] *= alpha; }
      l_run *= alpha;
      m_run = mn;
    }

    float p0[16], p1[16];
    float rs = 0.f;
#pragma unroll
    for (int i = 0; i < 16; ++i) {
      p0[i] = fexp2(fmaf(s0[i], SCALE, -m_run));
      p1[i] = fexp2(fmaf(s1[i], SCALE, -m_run));
      rs += p0[i] + p1[i];
    }
    rs += __shfl_xor(rs, 32, 64);
    l_run += rs;

    // ---- P^T -> PV B-frags in-register (cvt_pk + permlane32_swap) ----
    u32 w0[4][2], w1[4][2];
#pragma unroll
    for (int a = 0; a < 4; ++a) {
      w0[a][0] = cvtpk_bf16(p0[4 * a], p0[4 * a + 1]);
      w0[a][1] = cvtpk_bf16(p0[4 * a + 2], p0[4 * a + 3]);
      w1[a][0] = cvtpk_bf16(p1[4 * a], p1[4 * a + 1]);
      w1[a][1] = cvtpk_bf16(p1[4 * a + 2], p1[4 * a + 3]);
    }
    short8 pb[4];
#pragma unroll
    for (int ks = 0; ks < 4; ++ks) {
      int e = ks & 1;
      u32 x0 = (ks < 2) ? w0[2 * e][0] : w1[2 * e][0];
      u32 y0 = (ks < 2) ? w0[2 * e + 1][0] : w1[2 * e + 1][0];
      u32 x1 = (ks < 2) ? w0[2 * e][1] : w1[2 * e][1];
      u32 y1 = (ks < 2) ? w0[2 * e + 1][1] : w1[2 * e + 1][1];
      asm("v_permlane32_swap_b32 %0, %1" : "+v"(x0), "+v"(y0));
      asm("v_permlane32_swap_b32 %0, %1" : "+v"(x1), "+v"(y1));
      u32x4 tt = {x0, x1, y0, y1};  // words j={0,1},{2,3},{4,5},{6,7}
      pb[ks] = __builtin_bit_cast(short8, tt);
    }

    // ---- O^T += V^T . P^T ----
    const u16* Vc = Vg + cur * 4096;
    __builtin_amdgcn_s_setprio(1);
#pragma unroll
    for (int ks = 0; ks < 4; ++ks) {
      int ch0 = ((ks * 2 + hi) ^ (q5 & 7) ^ ((q5 >> 3) & 7)) * 8;
      int ch1 = ch0 ^ (4 * 8);  // row 32+q5: (d>>3) flips bit 2
      short8 v0 = *(const short8*)(Vc + q5 * 64 + ch0);
      short8 v1 = *(const short8*)(Vc + (32 + q5) * 64 + ch1);
      o0 = MFMA32(v0, pb[ks], o0);
      o1 = MFMA32(v1, pb[ks], o1);
    }
    __builtin_amdgcn_s_setprio(0);

    // ---- late V scatter into next buffer (vmcnt wait lands here) ----
    if (t < 15) vscatter(gtid, vna, vnb, Vg + nxt * 4096);

    __syncthreads();  // one barrier per tile: publishes K/V [nxt]
  }

  // ---- flash-combine of group 0/1 partials through LDS ----
  // overlay (K/V buffers dead; last loop barrier ordered all reads):
  // per gw: M[64] | L[64] | O[32][64]  (stride 2176 floats, conflict-free)
  float* sm = (float*)SM;
  float* base = sm + gw * 2176;
  if (g == 1) {
    base[lane] = m_run;
    base[64 + lane] = l_run;
#pragma unroll
    for (int i = 0; i < 16; ++i) {
      base[128 + i * 64 + lane] = o0[i];
      base[128 + (16 + i) * 64 + lane] = o1[i];
    }
  }
  __syncthreads();
  if (g == 0) {
    float m1 = base[lane], l1 = base[64 + lane];
    float M = fmaxf(m_run, m1);
    float w0 = fexp2(m_run - M), w1 = fexp2(m1 - M);
    float inv = 1.f / (w0 * l_run + w1 * l1);
    // epilogue: O^T[d][q], lane q5; d = (reg&3)+8*(reg>>2)+4*hi+32*dt
#pragma unroll
    for (int dt = 0; dt < 2; ++dt)
#pragma unroll
      for (int gq = 0; gq < 4; ++gq) {
        us4 st;
#pragma unroll
        for (int c2 = 0; c2 < 4; ++c2) {
          int i = 4 * gq + c2;
          float mine = (dt == 0) ? o0[i] : o1[i];
          float oth = base[128 + (dt * 16 + i) * 64 + lane];
          st[c2] = f2bf((w0 * mine + w1 * oth) * inv);
        }
        int col = h * 64 + dt * 32 + 8 * gq + 4 * hi;
        *(us4*)(attn_out + qrow * 1024 + col) = st;
      }
  }
}

// ================= launcher =================
extern "C" void kernel_launch(void* const* d_in, const int* in_sizes, int n_in,
                              void* d_out, int out_size, void* d_ws, size_t ws_size,
                              hipStream_t stream) {
  const float* x = (const float*)d_in[0];
  const float* Wqkv = (const float*)d_in[1];
  const float* Wproj = (const float*)d_in[2];
  const float* bproj = (const float*)d_in[3];
  float* out = (float*)d_out;

  char* ws = (char*)d_ws;
  u16* x_bf     = (u16*)(ws);                 //  8 MB  [4096,1024]
  u16* wqkv_bf  = (u16*)(ws + 8388608);       //  6 MB  [3072,1024]
  u16* wproj_bf = (u16*)(ws + 14680064);      //  2 MB  [1024,1024]
  u16* qkv_bf   = (u16*)(ws + 16777216);      // 24 MB  [4096,3072]
  u16* attn_bf  = (u16*)(ws + 41943040);      //  8 MB  [4096,1024]

  cvt_kernel<<<4096, 256, 0, stream>>>(x, x_bf, 1048576);
  cvt_kernel<<<3072, 256, 0, stream>>>(Wqkv, wqkv_bf, 786432);
  cvt_kernel<<<1024, 256, 0, stream>>>(Wproj, wproj_bf, 262144);

  dim3 g1(32, 24);
  gemm_bt<0><<<g1, 256, 0, stream>>>(x_bf, wqkv_bf, qkv_bf, nullptr, nullptr,
                                     4096, 3072, 1024);

  dim3 g2(16, 16, 2);
  attn_kernel<<<g2, 512, 0, stream>>>(qkv_bf, attn_bf);

  dim3 g3(32, 8);
  gemm_bt<1><<<g3, 256, 0, stream>>>(attn_bf, wproj_bf, nullptr, out, bproj,
                                     4096, 1024, 1024);
}

// Round 3
// 154.205 us; speedup vs baseline: 1.0348x; 1.0348x over previous
//
#include <hip/hip_runtime.h>

typedef unsigned short u16;
typedef unsigned int u32;
typedef __attribute__((ext_vector_type(8))) short short8;
typedef __attribute__((ext_vector_type(8))) __bf16 bf16x8;
typedef __attribute__((ext_vector_type(4))) float f32x4;
typedef __attribute__((ext_vector_type(16))) float f32x16;
typedef __attribute__((ext_vector_type(4))) unsigned short us4;
typedef __attribute__((ext_vector_type(4))) unsigned int u32x4;

#define DEVFN static __device__ __forceinline__

DEVFN u16 f2bf(float f) {
  u32 u = __float_as_uint(f);
  return (u16)((u + 0x7fffu + ((u >> 16) & 1u)) >> 16);  // RNE, finite inputs
}

#if __has_builtin(__builtin_amdgcn_exp2f)
DEVFN float fexp2(float x) { return __builtin_amdgcn_exp2f(x); }
#else
DEVFN float fexp2(float x) { return exp2f(x); }
#endif

// ---- MFMA wrappers: tolerant of short8-typed or bf16x8-typed builtins ----
template <typename T>
DEVFN auto mfma16_imp(T a, T b, f32x4 c, int)
    -> decltype(__builtin_amdgcn_mfma_f32_16x16x32_bf16(a, b, c, 0, 0, 0)) {
  return __builtin_amdgcn_mfma_f32_16x16x32_bf16(a, b, c, 0, 0, 0);
}
template <typename T>
DEVFN f32x4 mfma16_imp(T a, T b, f32x4 c, long) {
  return __builtin_amdgcn_mfma_f32_16x16x32_bf16(
      __builtin_bit_cast(bf16x8, a), __builtin_bit_cast(bf16x8, b), c, 0, 0, 0);
}
DEVFN f32x4 MFMA(short8 a, short8 b, f32x4 c) { return mfma16_imp(a, b, c, 0); }

template <typename T>
DEVFN auto mfma32_imp(T a, T b, f32x16 c, int)
    -> decltype(__builtin_amdgcn_mfma_f32_32x32x16_bf16(a, b, c, 0, 0, 0)) {
  return __builtin_amdgcn_mfma_f32_32x32x16_bf16(a, b, c, 0, 0, 0);
}
template <typename T>
DEVFN f32x16 mfma32_imp(T a, T b, f32x16 c, long) {
  return __builtin_amdgcn_mfma_f32_32x32x16_bf16(
      __builtin_bit_cast(bf16x8, a), __builtin_bit_cast(bf16x8, b), c, 0, 0, 0);
}
DEVFN f32x16 MFMA32(short8 a, short8 b, f32x16 c) { return mfma32_imp(a, b, c, 0); }

// ---- async global->LDS: dest = uniform base + lane*16 ----
DEVFN void gload_lds16(const u16* g, u16* l) {
  __builtin_amdgcn_global_load_lds(
      (__attribute__((address_space(1))) void*)g,
      (__attribute__((address_space(3))) void*)l, 16, 0, 0);
}

DEVFN u32 cvtpk_bf16(float lo, float hi) {
  u32 w;
  asm("v_cvt_pk_bf16_f32 %0, %1, %2" : "=v"(w) : "v"(lo), "v"(hi));
  return w;
}

// ================= f32 -> bf16 conversion =================
__global__ void __launch_bounds__(256) cvt_kernel(const float* __restrict__ in,
                                                  u16* __restrict__ out, int n4) {
  int i = blockIdx.x * 256 + threadIdx.x;
  if (i < n4) {
    f32x4 v = ((const f32x4*)in)[i];
    us4 o;
    o[0] = f2bf(v[0]); o[1] = f2bf(v[1]); o[2] = f2bf(v[2]); o[3] = f2bf(v[3]);
    ((us4*)out)[i] = o;
  }
}

// ================= GEMM: C[M,N] = A[M,K] @ B[N,K]^T (bf16 in, fp32 acc) ===
template <int F32OUT>
__global__ void __launch_bounds__(256) gemm_bt(
    const u16* __restrict__ A, const u16* __restrict__ Bm,
    u16* __restrict__ Cbf, float* __restrict__ Cf, const float* __restrict__ bias,
    int M, int N, int K) {
  __shared__ u16 As[128 * 32];
  __shared__ u16 Bs[128 * 32];
  const int tid = threadIdx.x;
  const int wave = tid >> 6, lane = tid & 63;
  const int bm = blockIdx.x * 128, bn = blockIdx.y * 128;
  const int wr = (wave >> 1) * 64, wc = (wave & 1) * 64;
  const int srow = lane >> 2, scol = (lane & 3) * 8;
  const int fr = lane & 15, fk = (lane >> 4) * 8;

  f32x4 acc[4][4] = {};

  for (int k0 = 0; k0 < K; k0 += 32) {
    __syncthreads();
#pragma unroll
    for (int t = 0; t < 2; ++t) {
      int rr = (wave * 2 + t) * 16 + srow;
      gload_lds16(A + (size_t)(bm + rr) * K + k0 + scol, As + (wave * 2 + t) * 512);
      gload_lds16(Bm + (size_t)(bn + rr) * K + k0 + scol, Bs + (wave * 2 + t) * 512);
    }
    __syncthreads();
    short8 af[4], bf[4];
#pragma unroll
    for (int i = 0; i < 4; ++i) {
      af[i] = *(const short8*)(As + (wr + i * 16 + fr) * 32 + fk);
      bf[i] = *(const short8*)(Bs + (wc + i * 16 + fr) * 32 + fk);
    }
#pragma unroll
    for (int mi = 0; mi < 4; ++mi)
#pragma unroll
      for (int ni = 0; ni < 4; ++ni)
        acc[mi][ni] = MFMA(af[mi], bf[ni], acc[mi][ni]);
  }

  const int orow = (lane >> 4) * 4, ocol = lane & 15;
#pragma unroll
  for (int mi = 0; mi < 4; ++mi)
#pragma unroll
    for (int ni = 0; ni < 4; ++ni)
#pragma unroll
      for (int r = 0; r < 4; ++r) {
        size_t row = (size_t)(bm + wr + mi * 16 + orow + r);
        size_t col = (size_t)(bn + wc + ni * 16 + ocol);
        if (F32OUT)
          Cf[row * N + col] = acc[mi][ni][r] + bias[col];
        else
          Cbf[row * N + col] = f2bf(acc[mi][ni][r]);
      }
}

// ================= Flash attention v4: V^T pre-transposed by GEMM ==========
// qk: [4096, 2048] bf16 (Q|K per token). vT: [1024, 4096] bf16 (vfeat, token).
// Grid (16 qblk, 16 heads, 2 batch), 256 thr (4 waves). Wave owns 32 q-rows
// (lane&31 = q); KVBLK=64; S^T = K.Q^T so softmax state is per-lane scalar;
// O^T = V^T.P^T; P redistributed in-register (cvt_pk+permlane32_swap).
// Both K and V^T staged via global_load_lds with source-folded XOR swizzle
// (zero VALU staging; the old 16x ds_write_b16 V-scatter is gone — V was
// transposed for free in the projection GEMM). Double-buffered, one barrier
// per tile, loads in flight across the whole compute phase.
__global__ void __launch_bounds__(256) attn_kernel(const u16* __restrict__ qk,
                                                   const u16* __restrict__ vT,
                                                   u16* __restrict__ attn_out) {
  __shared__ u16 Ks[2][64 * 64];  // K[kv][d],   chunk ^= (kv&7)
  __shared__ u16 Vs[2][64 * 64];  // V^T[d][kv], chunk ^= (d&7)^((d>>3)&7)

  const int tid = threadIdx.x;
  const int wave = tid >> 6, lane = tid & 63;
  const int q5 = lane & 31, hi = lane >> 5;
  const int qb = blockIdx.x, h = blockIdx.y, b = blockIdx.z;
  const size_t tok0 = (size_t)b * 2048;
  const float SCALE = 0.18033688011112042f;  // 0.125 * log2(e)

  // Q B-frags: lane q5 holds Q[q][ks*16 + hi*8 + j]
  const size_t qrow = tok0 + qb * 128 + wave * 32 + q5;
  const u16* qp = qk + qrow * 2048 + h * 64 + hi * 8;
  short8 qf[4];
#pragma unroll
  for (int ks = 0; ks < 4; ++ks) qf[ks] = *(const short8*)(qp + ks * 16);

  const u16* kbase = qk + tok0 * 2048 + 1024 + h * 64;       // + kv*2048
  const u16* vtb = vT + (size_t)h * 64 * 4096 + tok0;        // + d*4096 + kv

  // Static per-lane staging geometry: each wave covers rows rw*8..rw*8+7
  // for rw in {wave, 4+wave}; lane>>3 = row-in-8, lane&7 = LDS chunk.
  const int rowl = lane >> 3;
  const int k_srcoff = ((lane & 7) ^ rowl) * 8;  // K: key = (row&7) = rowl

  float m_run = -1e30f, l_run = 0.f;
  f32x16 o0 = {}, o1 = {};

  // ---- staging: 2 gload_lds16 each for K and V^T per thread per tile ----
#define STAGE(kv0, buf)                                                        \
  {                                                                            \
    _Pragma("unroll") for (int c = 0; c < 2; ++c) {                            \
      int rw = c * 4 + wave;                                                   \
      int row = rw * 8 + rowl;                                                 \
      gload_lds16(kbase + (size_t)((kv0) + row) * 2048 + k_srcoff,             \
                  Ks[buf] + rw * 512);                                         \
      int vso = (((lane & 7) ^ rowl ^ rw) * 8);  /* key = (d&7)^((d>>3)&7) */  \
      gload_lds16(vtb + (size_t)row * 4096 + (kv0) + vso, Vs[buf] + rw * 512); \
    }                                                                          \
  }

  STAGE(0, 0);
  __syncthreads();

  for (int t = 0; t < 32; ++t) {
    const int cur = t & 1, nxt = cur ^ 1;
    if (t < 31) STAGE((t + 1) * 64, nxt);  // in flight across whole compute

    // ---- S^T = K . Q^T : 2 tiles (kv 0-31 / 32-63), 4 k-steps ----
    const u16* Kc = Ks[cur];
    f32x16 s0 = {}, s1 = {};
    __builtin_amdgcn_s_setprio(1);
#pragma unroll
    for (int ks = 0; ks < 4; ++ks) {
      int ch = ((ks * 2 + hi) ^ (q5 & 7)) * 8;
      short8 k0 = *(const short8*)(Kc + q5 * 64 + ch);
      short8 k1 = *(const short8*)(Kc + (32 + q5) * 64 + ch);
      s0 = MFMA32(k0, qf[ks], s0);
      s1 = MFMA32(k1, qf[ks], s1);
    }
    __builtin_amdgcn_s_setprio(0);

    // ---- online softmax, per-lane scalars (lane owns q = q5) ----
    float mt[8];
#pragma unroll
    for (int i = 0; i < 8; ++i)
      mt[i] = fmaxf(fmaxf(s0[i], s0[i + 8]), fmaxf(s1[i], s1[i + 8]));
    float pmax = fmaxf(fmaxf(fmaxf(mt[0], mt[1]), fmaxf(mt[2], mt[3])),
                       fmaxf(fmaxf(mt[4], mt[5]), fmaxf(mt[6], mt[7])));
    pmax = fmaxf(pmax, __shfl_xor(pmax, 32, 64));
    float mraw = pmax * SCALE;

    if (__any(mraw > m_run + 8.f)) {  // T13 defer-max, wave-uniform
      float mn = fmaxf(m_run, mraw);
      float alpha = fexp2(m_run - mn);
#pragma unroll
      for (int i = 0; i < 16; ++i) { o0[i] *= alpha; o1[i] *= alpha; }
      l_run *= alpha;
      m_run = mn;
    }

    float p0[16], p1[16];
    float rs = 0.f;
#pragma unroll
    for (int i = 0; i < 16; ++i) {
      p0[i] = fexp2(fmaf(s0[i], SCALE, -m_run));
      p1[i] = fexp2(fmaf(s1[i], SCALE, -m_run));
      rs += p0[i] + p1[i];
    }
    rs += __shfl_xor(rs, 32, 64);
    l_run += rs;

    // ---- P^T -> PV B-frags in-register (cvt_pk + permlane32_swap) ----
    u32 w0[4][2], w1[4][2];
#pragma unroll
    for (int a = 0; a < 4; ++a) {
      w0[a][0] = cvtpk_bf16(p0[4 * a], p0[4 * a + 1]);
      w0[a][1] = cvtpk_bf16(p0[4 * a + 2], p0[4 * a + 3]);
      w1[a][0] = cvtpk_bf16(p1[4 * a], p1[4 * a + 1]);
      w1[a][1] = cvtpk_bf16(p1[4 * a + 2], p1[4 * a + 3]);
    }
    short8 pb[4];
#pragma unroll
    for (int ks = 0; ks < 4; ++ks) {
      int e = ks & 1;
      u32 x0 = (ks < 2) ? w0[2 * e][0] : w1[2 * e][0];
      u32 y0 = (ks < 2) ? w0[2 * e + 1][0] : w1[2 * e + 1][0];
      u32 x1 = (ks < 2) ? w0[2 * e][1] : w1[2 * e][1];
      u32 y1 = (ks < 2) ? w0[2 * e + 1][1] : w1[2 * e + 1][1];
      asm("v_permlane32_swap_b32 %0, %1" : "+v"(x0), "+v"(y0));
      asm("v_permlane32_swap_b32 %0, %1" : "+v"(x1), "+v"(y1));
      u32x4 tt = {x0, x1, y0, y1};  // words j={0,1},{2,3},{4,5},{6,7}
      pb[ks] = __builtin_bit_cast(short8, tt);
    }

    // ---- O^T += V^T . P^T ----
    const u16* Vc = Vs[cur];
    __builtin_amdgcn_s_setprio(1);
#pragma unroll
    for (int ks = 0; ks < 4; ++ks) {
      int ch0 = ((ks * 2 + hi) ^ (q5 & 7) ^ ((q5 >> 3) & 7)) * 8;
      int ch1 = ch0 ^ (4 * 8);  // row 32+q5: (d>>3) flips bit 2
      short8 v0 = *(const short8*)(Vc + q5 * 64 + ch0);
      short8 v1 = *(const short8*)(Vc + (32 + q5) * 64 + ch1);
      o0 = MFMA32(v0, pb[ks], o0);
      o1 = MFMA32(v1, pb[ks], o1);
    }
    __builtin_amdgcn_s_setprio(0);

    __syncthreads();  // one barrier per tile: publishes Ks/Vs[nxt]
  }
#undef STAGE

  // ---- epilogue: O^T[d][q], lane q5; d = (reg&3)+8*(reg>>2)+4*hi+32*dt ----
  float inv = 1.f / l_run;
#pragma unroll
  for (int dt = 0; dt < 2; ++dt)
#pragma unroll
    for (int g = 0; g < 4; ++g) {
      us4 st;
#pragma unroll
      for (int c2 = 0; c2 < 4; ++c2) {
        float val = (dt == 0 ? o0[4 * g + c2] : o1[4 * g + c2]) * inv;
        st[c2] = f2bf(val);
      }
      int col = h * 64 + dt * 32 + 8 * g + 4 * hi;
      *(us4*)(attn_out + qrow * 1024 + col) = st;
    }
}

// ================= launcher =================
extern "C" void kernel_launch(void* const* d_in, const int* in_sizes, int n_in,
                              void* d_out, int out_size, void* d_ws, size_t ws_size,
                              hipStream_t stream) {
  const float* x = (const float*)d_in[0];
  const float* Wqkv = (const float*)d_in[1];
  const float* Wproj = (const float*)d_in[2];
  const float* bproj = (const float*)d_in[3];
  float* out = (float*)d_out;

  char* ws = (char*)d_ws;
  u16* x_bf     = (u16*)(ws);                 //  8 MB  [4096,1024]
  u16* wqkv_bf  = (u16*)(ws + 8388608);       //  6 MB  [3072,1024]
  u16* wproj_bf = (u16*)(ws + 14680064);      //  2 MB  [1024,1024]
  u16* qk_bf    = (u16*)(ws + 16777216);      // 16 MB  [4096,2048] (Q|K)
  u16* vt_bf    = (u16*)(ws + 33554432);      //  8 MB  [1024,4096] V^T
  u16* attn_bf  = (u16*)(ws + 41943040);      //  8 MB  [4096,1024]

  cvt_kernel<<<4096, 256, 0, stream>>>(x, x_bf, 1048576);
  cvt_kernel<<<3072, 256, 0, stream>>>(Wqkv, wqkv_bf, 786432);
  cvt_kernel<<<1024, 256, 0, stream>>>(Wproj, wproj_bf, 262144);

  // Q,K projection: [4096,2048] = x @ Wqk^T
  dim3 gq(32, 16);
  gemm_bt<0><<<gq, 256, 0, stream>>>(x_bf, wqkv_bf, qk_bf, nullptr, nullptr,
                                     4096, 2048, 1024);
  // V^T projection: [1024,4096] = Wv @ x^T  (same kernel, operands swapped)
  dim3 gv(8, 32);
  gemm_bt<0><<<gv, 256, 0, stream>>>(wqkv_bf + (size_t)2048 * 1024, x_bf, vt_bf,
                                     nullptr, nullptr, 1024, 4096, 1024);

  dim3 g2(16, 16, 2);
  attn_kernel<<<g2, 256, 0, stream>>>(qk_bf, vt_bf, attn_bf);

  dim3 g3(32, 8);
  gemm_bt<1><<<g3, 256, 0, stream>>>(attn_bf, wproj_bf, nullptr, out, bproj,
                                     4096, 1024, 1024);
}

// Round 4
// 131.025 us; speedup vs baseline: 1.2178x; 1.1769x over previous
//
#include <hip/hip_runtime.h>

typedef unsigned short u16;
typedef unsigned int u32;
typedef __attribute__((ext_vector_type(8))) short short8;
typedef __attribute__((ext_vector_type(8))) __bf16 bf16x8;
typedef __attribute__((ext_vector_type(4))) float f32x4;
typedef __attribute__((ext_vector_type(16))) float f32x16;
typedef __attribute__((ext_vector_type(4))) unsigned short us4;
typedef __attribute__((ext_vector_type(4))) unsigned int u32x4;

#define DEVFN static __device__ __forceinline__

DEVFN u16 f2bf(float f) {
  u32 u = __float_as_uint(f);
  return (u16)((u + 0x7fffu + ((u >> 16) & 1u)) >> 16);  // RNE, finite inputs
}

#if __has_builtin(__builtin_amdgcn_exp2f)
DEVFN float fexp2(float x) { return __builtin_amdgcn_exp2f(x); }
#else
DEVFN float fexp2(float x) { return exp2f(x); }
#endif

// ---- MFMA wrappers: tolerant of short8-typed or bf16x8-typed builtins ----
template <typename T>
DEVFN auto mfma16_imp(T a, T b, f32x4 c, int)
    -> decltype(__builtin_amdgcn_mfma_f32_16x16x32_bf16(a, b, c, 0, 0, 0)) {
  return __builtin_amdgcn_mfma_f32_16x16x32_bf16(a, b, c, 0, 0, 0);
}
template <typename T>
DEVFN f32x4 mfma16_imp(T a, T b, f32x4 c, long) {
  return __builtin_amdgcn_mfma_f32_16x16x32_bf16(
      __builtin_bit_cast(bf16x8, a), __builtin_bit_cast(bf16x8, b), c, 0, 0, 0);
}
DEVFN f32x4 MFMA(short8 a, short8 b, f32x4 c) { return mfma16_imp(a, b, c, 0); }

template <typename T>
DEVFN auto mfma32_imp(T a, T b, f32x16 c, int)
    -> decltype(__builtin_amdgcn_mfma_f32_32x32x16_bf16(a, b, c, 0, 0, 0)) {
  return __builtin_amdgcn_mfma_f32_32x32x16_bf16(a, b, c, 0, 0, 0);
}
template <typename T>
DEVFN f32x16 mfma32_imp(T a, T b, f32x16 c, long) {
  return __builtin_amdgcn_mfma_f32_32x32x16_bf16(
      __builtin_bit_cast(bf16x8, a), __builtin_bit_cast(bf16x8, b), c, 0, 0, 0);
}
DEVFN f32x16 MFMA32(short8 a, short8 b, f32x16 c) { return mfma32_imp(a, b, c, 0); }

// ---- async global->LDS: dest = uniform base + lane*16 ----
DEVFN void gload_lds16(const u16* g, u16* l) {
  __builtin_amdgcn_global_load_lds(
      (__attribute__((address_space(1))) void*)g,
      (__attribute__((address_space(3))) void*)l, 16, 0, 0);
}

DEVFN u32 cvtpk_bf16(float lo, float hi) {
  u32 w;
  asm("v_cvt_pk_bf16_f32 %0, %1, %2" : "=v"(w) : "v"(lo), "v"(hi));
  return w;
}

// ================= fused f32 -> bf16 conversion (one launch) =============
// regions: x 1048576 f32x4 groups, Wqkv 786432, Wproj 262144 — all multiples
// of 256, so each block maps to exactly one region (uniform branch).
__global__ void __launch_bounds__(256) cvt_all(
    const float* __restrict__ x, u16* __restrict__ xo,
    const float* __restrict__ w1, u16* __restrict__ w1o,
    const float* __restrict__ w2, u16* __restrict__ w2o) {
  int bid = blockIdx.x;
  const float* in;
  u16* out;
  int i;
  if (bid < 4096) {
    in = x; out = xo; i = bid * 256 + threadIdx.x;
  } else if (bid < 7168) {
    in = w1; out = w1o; i = (bid - 4096) * 256 + threadIdx.x;
  } else {
    in = w2; out = w2o; i = (bid - 7168) * 256 + threadIdx.x;
  }
  f32x4 v = ((const f32x4*)in)[i];
  us4 o;
  o[0] = f2bf(v[0]); o[1] = f2bf(v[1]); o[2] = f2bf(v[2]); o[3] = f2bf(v[3]);
  ((us4*)out)[i] = o;
}

// ====== GEMM tile body: C[bm:bm+128, bn:bn+128] = A[M,K] @ B[N,K]^T =======
template <int F32OUT>
DEVFN void gemm_tile(const u16* __restrict__ A, const u16* __restrict__ Bm,
                     u16* __restrict__ Cbf, float* __restrict__ Cf,
                     const float* __restrict__ bias, int N, int K, int bm,
                     int bn, u16* As, u16* Bs) {
  const int tid = threadIdx.x;
  const int wave = tid >> 6, lane = tid & 63;
  const int wr = (wave >> 1) * 64, wc = (wave & 1) * 64;
  const int srow = lane >> 2, scol = (lane & 3) * 8;
  const int fr = lane & 15, fk = (lane >> 4) * 8;

  f32x4 acc[4][4] = {};

  for (int k0 = 0; k0 < K; k0 += 32) {
    __syncthreads();
#pragma unroll
    for (int t = 0; t < 2; ++t) {
      int rr = (wave * 2 + t) * 16 + srow;
      gload_lds16(A + (size_t)(bm + rr) * K + k0 + scol, As + (wave * 2 + t) * 512);
      gload_lds16(Bm + (size_t)(bn + rr) * K + k0 + scol, Bs + (wave * 2 + t) * 512);
    }
    __syncthreads();
    short8 af[4], bf[4];
#pragma unroll
    for (int i = 0; i < 4; ++i) {
      af[i] = *(const short8*)(As + (wr + i * 16 + fr) * 32 + fk);
      bf[i] = *(const short8*)(Bs + (wc + i * 16 + fr) * 32 + fk);
    }
#pragma unroll
    for (int mi = 0; mi < 4; ++mi)
#pragma unroll
      for (int ni = 0; ni < 4; ++ni)
        acc[mi][ni] = MFMA(af[mi], bf[ni], acc[mi][ni]);
  }

  const int orow = (lane >> 4) * 4, ocol = lane & 15;
#pragma unroll
  for (int mi = 0; mi < 4; ++mi)
#pragma unroll
    for (int ni = 0; ni < 4; ++ni)
#pragma unroll
      for (int r = 0; r < 4; ++r) {
        size_t row = (size_t)(bm + wr + mi * 16 + orow + r);
        size_t col = (size_t)(bn + wc + ni * 16 + ocol);
        if (F32OUT)
          Cf[row * N + col] = acc[mi][ni][r] + bias[col];
        else
          Cbf[row * N + col] = f2bf(acc[mi][ni][r]);
      }
}

// ================= standalone GEMM (used for the output projection) =======
template <int F32OUT>
__global__ void __launch_bounds__(256) gemm_bt(
    const u16* __restrict__ A, const u16* __restrict__ Bm,
    u16* __restrict__ Cbf, float* __restrict__ Cf, const float* __restrict__ bias,
    int M, int N, int K) {
  __shared__ u16 As[128 * 32];
  __shared__ u16 Bs[128 * 32];
  gemm_tile<F32OUT>(A, Bm, Cbf, Cf, bias, N, K, blockIdx.x * 128,
                    blockIdx.y * 128, As, Bs);
}

// ====== fused projection: QK = x @ Wqk^T  and  V^T = Wv @ x^T =============
// One 768-block launch so both sub-GEMMs are co-resident (the R3 split gave
// the V^T GEMM only 1 block/CU -> exposed barrier drains, +18 us).
// blocks [0,512): QK tiles, grid 32x16 over [4096, 2048].
// blocks [512,768): V^T tiles, grid 8x32 over [1024, 4096] (A=Wv, B=x).
__global__ void __launch_bounds__(256) fused_qkv_gemm(
    const u16* __restrict__ x, const u16* __restrict__ wqkv,
    u16* __restrict__ qk, u16* __restrict__ vt) {
  __shared__ u16 As[128 * 32];
  __shared__ u16 Bs[128 * 32];
  int bid = blockIdx.x;
  if (bid < 512) {
    gemm_tile<0>(x, wqkv, qk, nullptr, nullptr, 2048, 1024, (bid & 31) * 128,
                 (bid >> 5) * 128, As, Bs);
  } else {
    int j = bid - 512;
    gemm_tile<0>(wqkv + (size_t)2048 * 1024, x, vt, nullptr, nullptr, 4096,
                 1024, (j & 7) * 128, (j >> 3) * 128, As, Bs);
  }
}

// ================= Flash attention v4: V^T pre-transposed by GEMM ==========
// qk: [4096, 2048] bf16 (Q|K per token). vT: [1024, 4096] bf16 (vfeat, token).
// Grid (16 qblk, 16 heads, 2 batch), 256 thr (4 waves). Wave owns 32 q-rows
// (lane&31 = q); KVBLK=64; S^T = K.Q^T so softmax state is per-lane scalar;
// O^T = V^T.P^T; P redistributed in-register (cvt_pk+permlane32_swap).
// Both K and V^T staged via global_load_lds with source-folded XOR swizzle.
__global__ void __launch_bounds__(256) attn_kernel(const u16* __restrict__ qk,
                                                   const u16* __restrict__ vT,
                                                   u16* __restrict__ attn_out) {
  __shared__ u16 Ks[2][64 * 64];  // K[kv][d],   chunk ^= (kv&7)
  __shared__ u16 Vs[2][64 * 64];  // V^T[d][kv], chunk ^= (d&7)^((d>>3)&7)

  const int tid = threadIdx.x;
  const int wave = tid >> 6, lane = tid & 63;
  const int q5 = lane & 31, hi = lane >> 5;
  const int qb = blockIdx.x, h = blockIdx.y, b = blockIdx.z;
  const size_t tok0 = (size_t)b * 2048;
  const float SCALE = 0.18033688011112042f;  // 0.125 * log2(e)

  // Q B-frags: lane q5 holds Q[q][ks*16 + hi*8 + j]
  const size_t qrow = tok0 + qb * 128 + wave * 32 + q5;
  const u16* qp = qk + qrow * 2048 + h * 64 + hi * 8;
  short8 qf[4];
#pragma unroll
  for (int ks = 0; ks < 4; ++ks) qf[ks] = *(const short8*)(qp + ks * 16);

  const u16* kbase = qk + tok0 * 2048 + 1024 + h * 64;       // + kv*2048
  const u16* vtb = vT + (size_t)h * 64 * 4096 + tok0;        // + d*4096 + kv

  // Static per-lane staging geometry: each wave covers rows rw*8..rw*8+7
  // for rw in {wave, 4+wave}; lane>>3 = row-in-8, lane&7 = LDS chunk.
  const int rowl = lane >> 3;
  const int k_srcoff = ((lane & 7) ^ rowl) * 8;  // K: key = (row&7) = rowl

  float m_run = -1e30f, l_run = 0.f;
  f32x16 o0 = {}, o1 = {};

  // ---- staging: 2 gload_lds16 each for K and V^T per thread per tile ----
#define STAGE(kv0, buf)                                                        \
  {                                                                            \
    _Pragma("unroll") for (int c = 0; c < 2; ++c) {                            \
      int rw = c * 4 + wave;                                                   \
      int row = rw * 8 + rowl;                                                 \
      gload_lds16(kbase + (size_t)((kv0) + row) * 2048 + k_srcoff,             \
                  Ks[buf] + rw * 512);                                         \
      int vso = (((lane & 7) ^ rowl ^ rw) * 8);  /* key = (d&7)^((d>>3)&7) */  \
      gload_lds16(vtb + (size_t)row * 4096 + (kv0) + vso, Vs[buf] + rw * 512); \
    }                                                                          \
  }

  STAGE(0, 0);
  __syncthreads();

  for (int t = 0; t < 32; ++t) {
    const int cur = t & 1, nxt = cur ^ 1;
    if (t < 31) STAGE((t + 1) * 64, nxt);  // in flight across whole compute

    // ---- S^T = K . Q^T : 2 tiles (kv 0-31 / 32-63), 4 k-steps ----
    const u16* Kc = Ks[cur];
    f32x16 s0 = {}, s1 = {};
    __builtin_amdgcn_s_setprio(1);
#pragma unroll
    for (int ks = 0; ks < 4; ++ks) {
      int ch = ((ks * 2 + hi) ^ (q5 & 7)) * 8;
      short8 k0 = *(const short8*)(Kc + q5 * 64 + ch);
      short8 k1 = *(const short8*)(Kc + (32 + q5) * 64 + ch);
      s0 = MFMA32(k0, qf[ks], s0);
      s1 = MFMA32(k1, qf[ks], s1);
    }
    __builtin_amdgcn_s_setprio(0);

    // ---- online softmax, per-lane scalars (lane owns q = q5) ----
    float mt[8];
#pragma unroll
    for (int i = 0; i < 8; ++i)
      mt[i] = fmaxf(fmaxf(s0[i], s0[i + 8]), fmaxf(s1[i], s1[i + 8]));
    float pmax = fmaxf(fmaxf(fmaxf(mt[0], mt[1]), fmaxf(mt[2], mt[3])),
                       fmaxf(fmaxf(mt[4], mt[5]), fmaxf(mt[6], mt[7])));
    pmax = fmaxf(pmax, __shfl_xor(pmax, 32, 64));
    float mraw = pmax * SCALE;

    if (__any(mraw > m_run + 8.f)) {  // T13 defer-max, wave-uniform
      float mn = fmaxf(m_run, mraw);
      float alpha = fexp2(m_run - mn);
#pragma unroll
      for (int i = 0; i < 16; ++i) { o0[i] *= alpha; o1[i] *= alpha; }
      l_run *= alpha;
      m_run = mn;
    }

    float p0[16], p1[16];
    float rs = 0.f;
#pragma unroll
    for (int i = 0; i < 16; ++i) {
      p0[i] = fexp2(fmaf(s0[i], SCALE, -m_run));
      p1[i] = fexp2(fmaf(s1[i], SCALE, -m_run));
      rs += p0[i] + p1[i];
    }
    rs += __shfl_xor(rs, 32, 64);
    l_run += rs;

    // ---- P^T -> PV B-frags in-register (cvt_pk + permlane32_swap) ----
    u32 w0[4][2], w1[4][2];
#pragma unroll
    for (int a = 0; a < 4; ++a) {
      w0[a][0] = cvtpk_bf16(p0[4 * a], p0[4 * a + 1]);
      w0[a][1] = cvtpk_bf16(p0[4 * a + 2], p0[4 * a + 3]);
      w1[a][0] = cvtpk_bf16(p1[4 * a], p1[4 * a + 1]);
      w1[a][1] = cvtpk_bf16(p1[4 * a + 2], p1[4 * a + 3]);
    }
    short8 pb[4];
#pragma unroll
    for (int ks = 0; ks < 4; ++ks) {
      int e = ks & 1;
      u32 x0 = (ks < 2) ? w0[2 * e][0] : w1[2 * e][0];
      u32 y0 = (ks < 2) ? w0[2 * e + 1][0] : w1[2 * e + 1][0];
      u32 x1 = (ks < 2) ? w0[2 * e][1] : w1[2 * e][1];
      u32 y1 = (ks < 2) ? w0[2 * e + 1][1] : w1[2 * e + 1][1];
      asm("v_permlane32_swap_b32 %0, %1" : "+v"(x0), "+v"(y0));
      asm("v_permlane32_swap_b32 %0, %1" : "+v"(x1), "+v"(y1));
      u32x4 tt = {x0, x1, y0, y1};  // words j={0,1},{2,3},{4,5},{6,7}
      pb[ks] = __builtin_bit_cast(short8, tt);
    }

    // ---- O^T += V^T . P^T ----
    const u16* Vc = Vs[cur];
    __builtin_amdgcn_s_setprio(1);
#pragma unroll
    for (int ks = 0; ks < 4; ++ks) {
      int ch0 = ((ks * 2 + hi) ^ (q5 & 7) ^ ((q5 >> 3) & 7)) * 8;
      int ch1 = ch0 ^ (4 * 8);  // row 32+q5: (d>>3) flips bit 2
      short8 v0 = *(const short8*)(Vc + q5 * 64 + ch0);
      short8 v1 = *(const short8*)(Vc + (32 + q5) * 64 + ch1);
      o0 = MFMA32(v0, pb[ks], o0);
      o1 = MFMA32(v1, pb[ks], o1);
    }
    __builtin_amdgcn_s_setprio(0);

    __syncthreads();  // one barrier per tile: publishes Ks/Vs[nxt]
  }
#undef STAGE

  // ---- epilogue: O^T[d][q], lane q5; d = (reg&3)+8*(reg>>2)+4*hi+32*dt ----
  float inv = 1.f / l_run;
#pragma unroll
  for (int dt = 0; dt < 2; ++dt)
#pragma unroll
    for (int g = 0; g < 4; ++g) {
      us4 st;
#pragma unroll
      for (int c2 = 0; c2 < 4; ++c2) {
        float val = (dt == 0 ? o0[4 * g + c2] : o1[4 * g + c2]) * inv;
        st[c2] = f2bf(val);
      }
      int col = h * 64 + dt * 32 + 8 * g + 4 * hi;
      *(us4*)(attn_out + qrow * 1024 + col) = st;
    }
}

// ================= launcher =================
extern "C" void kernel_launch(void* const* d_in, const int* in_sizes, int n_in,
                              void* d_out, int out_size, void* d_ws, size_t ws_size,
                              hipStream_t stream) {
  const float* x = (const float*)d_in[0];
  const float* Wqkv = (const float*)d_in[1];
  const float* Wproj = (const float*)d_in[2];
  const float* bproj = (const float*)d_in[3];
  float* out = (float*)d_out;

  char* ws = (char*)d_ws;
  u16* x_bf     = (u16*)(ws);                 //  8 MB  [4096,1024]
  u16* wqkv_bf  = (u16*)(ws + 8388608);       //  6 MB  [3072,1024]
  u16* wproj_bf = (u16*)(ws + 14680064);      //  2 MB  [1024,1024]
  u16* qk_bf    = (u16*)(ws + 16777216);      // 16 MB  [4096,2048] (Q|K)
  u16* vt_bf    = (u16*)(ws + 33554432);      //  8 MB  [1024,4096] V^T
  u16* attn_bf  = (u16*)(ws + 41943040);      //  8 MB  [4096,1024]

  cvt_all<<<8192, 256, 0, stream>>>(x, x_bf, Wqkv, wqkv_bf, Wproj, wproj_bf);

  fused_qkv_gemm<<<768, 256, 0, stream>>>(x_bf, wqkv_bf, qk_bf, vt_bf);

  dim3 g2(16, 16, 2);
  attn_kernel<<<g2, 256, 0, stream>>>(qk_bf, vt_bf, attn_bf);

  dim3 g3(32, 8);
  gemm_bt<1><<<g3, 256, 0, stream>>>(attn_bf, wproj_bf, nullptr, out, bproj,
                                     4096, 1024, 1024);
}

// Round 5
// 125.337 us; speedup vs baseline: 1.2731x; 1.0454x over previous
//
#include <hip/hip_runtime.h>

typedef unsigned short u16;
typedef unsigned int u32;
typedef __attribute__((ext_vector_type(8))) short short8;
typedef __attribute__((ext_vector_type(8))) __bf16 bf16x8;
typedef __attribute__((ext_vector_type(4))) float f32x4;
typedef __attribute__((ext_vector_type(16))) float f32x16;
typedef __attribute__((ext_vector_type(4))) unsigned short us4;
typedef __attribute__((ext_vector_type(4))) unsigned int u32x4;

#define DEVFN static __device__ __forceinline__

DEVFN u16 f2bf(float f) {
  u32 u = __float_as_uint(f);
  return (u16)((u + 0x7fffu + ((u >> 16) & 1u)) >> 16);  // RNE, finite inputs
}

#if __has_builtin(__builtin_amdgcn_exp2f)
DEVFN float fexp2(float x) { return __builtin_amdgcn_exp2f(x); }
#else
DEVFN float fexp2(float x) { return exp2f(x); }
#endif

// ---- MFMA wrappers: tolerant of short8-typed or bf16x8-typed builtins ----
template <typename T>
DEVFN auto mfma16_imp(T a, T b, f32x4 c, int)
    -> decltype(__builtin_amdgcn_mfma_f32_16x16x32_bf16(a, b, c, 0, 0, 0)) {
  return __builtin_amdgcn_mfma_f32_16x16x32_bf16(a, b, c, 0, 0, 0);
}
template <typename T>
DEVFN f32x4 mfma16_imp(T a, T b, f32x4 c, long) {
  return __builtin_amdgcn_mfma_f32_16x16x32_bf16(
      __builtin_bit_cast(bf16x8, a), __builtin_bit_cast(bf16x8, b), c, 0, 0, 0);
}
DEVFN f32x4 MFMA(short8 a, short8 b, f32x4 c) { return mfma16_imp(a, b, c, 0); }

template <typename T>
DEVFN auto mfma32_imp(T a, T b, f32x16 c, int)
    -> decltype(__builtin_amdgcn_mfma_f32_32x32x16_bf16(a, b, c, 0, 0, 0)) {
  return __builtin_amdgcn_mfma_f32_32x32x16_bf16(a, b, c, 0, 0, 0);
}
template <typename T>
DEVFN f32x16 mfma32_imp(T a, T b, f32x16 c, long) {
  return __builtin_amdgcn_mfma_f32_32x32x16_bf16(
      __builtin_bit_cast(bf16x8, a), __builtin_bit_cast(bf16x8, b), c, 0, 0, 0);
}
DEVFN f32x16 MFMA32(short8 a, short8 b, f32x16 c) { return mfma32_imp(a, b, c, 0); }

// ---- async global->LDS: dest = uniform base + lane*16 ----
DEVFN void gload_lds16(const u16* g, u16* l) {
  __builtin_amdgcn_global_load_lds(
      (__attribute__((address_space(1))) void*)g,
      (__attribute__((address_space(3))) void*)l, 16, 0, 0);
}

DEVFN u32 cvtpk_bf16(float lo, float hi) {
  u32 w;
  asm("v_cvt_pk_bf16_f32 %0, %1, %2" : "=v"(w) : "v"(lo), "v"(hi));
  return w;
}

// ================= fused f32 -> bf16 conversion (one launch) =============
__global__ void __launch_bounds__(256) cvt_all(
    const float* __restrict__ x, u16* __restrict__ xo,
    const float* __restrict__ w1, u16* __restrict__ w1o,
    const float* __restrict__ w2, u16* __restrict__ w2o) {
  int bid = blockIdx.x;
  const float* in;
  u16* out;
  int i;
  if (bid < 4096) {
    in = x; out = xo; i = bid * 256 + threadIdx.x;
  } else if (bid < 7168) {
    in = w1; out = w1o; i = (bid - 4096) * 256 + threadIdx.x;
  } else {
    in = w2; out = w2o; i = (bid - 7168) * 256 + threadIdx.x;
  }
  f32x4 v = ((const f32x4*)in)[i];
  us4 o;
  o[0] = f2bf(v[0]); o[1] = f2bf(v[1]); o[2] = f2bf(v[2]); o[3] = f2bf(v[3]);
  ((us4*)out)[i] = o;
}

// ====== GEMM tile body: C[bm:bm+128, bn:bn+128] = A[M,K] @ B[N,K]^T =======
template <int F32OUT>
DEVFN void gemm_tile(const u16* __restrict__ A, const u16* __restrict__ Bm,
                     u16* __restrict__ Cbf, float* __restrict__ Cf,
                     const float* __restrict__ bias, int N, int K, int bm,
                     int bn, u16* As, u16* Bs) {
  const int tid = threadIdx.x;
  const int wave = tid >> 6, lane = tid & 63;
  const int wr = (wave >> 1) * 64, wc = (wave & 1) * 64;
  const int srow = lane >> 2, scol = (lane & 3) * 8;
  const int fr = lane & 15, fk = (lane >> 4) * 8;

  f32x4 acc[4][4] = {};

  for (int k0 = 0; k0 < K; k0 += 32) {
    __syncthreads();
#pragma unroll
    for (int t = 0; t < 2; ++t) {
      int rr = (wave * 2 + t) * 16 + srow;
      gload_lds16(A + (size_t)(bm + rr) * K + k0 + scol, As + (wave * 2 + t) * 512);
      gload_lds16(Bm + (size_t)(bn + rr) * K + k0 + scol, Bs + (wave * 2 + t) * 512);
    }
    __syncthreads();
    short8 af[4], bf[4];
#pragma unroll
    for (int i = 0; i < 4; ++i) {
      af[i] = *(const short8*)(As + (wr + i * 16 + fr) * 32 + fk);
      bf[i] = *(const short8*)(Bs + (wc + i * 16 + fr) * 32 + fk);
    }
#pragma unroll
    for (int mi = 0; mi < 4; ++mi)
#pragma unroll
      for (int ni = 0; ni < 4; ++ni)
        acc[mi][ni] = MFMA(af[mi], bf[ni], acc[mi][ni]);
  }

  const int orow = (lane >> 4) * 4, ocol = lane & 15;
#pragma unroll
  for (int mi = 0; mi < 4; ++mi)
#pragma unroll
    for (int ni = 0; ni < 4; ++ni)
#pragma unroll
      for (int r = 0; r < 4; ++r) {
        size_t row = (size_t)(bm + wr + mi * 16 + orow + r);
        size_t col = (size_t)(bn + wc + ni * 16 + ocol);
        if (F32OUT)
          Cf[row * N + col] = acc[mi][ni][r] + bias[col];
        else
          Cbf[row * N + col] = f2bf(acc[mi][ni][r]);
      }
}

// ================= standalone GEMM (used for the output projection) =======
template <int F32OUT>
__global__ void __launch_bounds__(256) gemm_bt(
    const u16* __restrict__ A, const u16* __restrict__ Bm,
    u16* __restrict__ Cbf, float* __restrict__ Cf, const float* __restrict__ bias,
    int M, int N, int K) {
  __shared__ u16 As[128 * 32];
  __shared__ u16 Bs[128 * 32];
  gemm_tile<F32OUT>(A, Bm, Cbf, Cf, bias, N, K, blockIdx.x * 128,
                    blockIdx.y * 128, As, Bs);
}

// ====== fused projection: QK = x @ Wqk^T  and  V^T = Wv @ x^T =============
// One 768-block launch so both sub-GEMMs are co-resident.
__global__ void __launch_bounds__(256) fused_qkv_gemm(
    const u16* __restrict__ x, const u16* __restrict__ wqkv,
    u16* __restrict__ qk, u16* __restrict__ vt) {
  __shared__ u16 As[128 * 32];
  __shared__ u16 Bs[128 * 32];
  int bid = blockIdx.x;
  if (bid < 512) {
    gemm_tile<0>(x, wqkv, qk, nullptr, nullptr, 2048, 1024, (bid & 31) * 128,
                 (bid >> 5) * 128, As, Bs);
  } else {
    int j = bid - 512;
    gemm_tile<0>(wqkv + (size_t)2048 * 1024, x, vt, nullptr, nullptr, 4096,
                 1024, (j & 7) * 128, (j >> 3) * 128, As, Bs);
  }
}

// ================= Flash attention v5: v4 + in-block KV-split x2 ==========
// qk: [4096, 2048] bf16 (Q|K). vT: [1024, 4096] bf16 (vfeat, token).
// Grid (16 qblk, 16 heads, 2 batch), 512 thr (8 waves). Waves 0-3 (group 0)
// process kv [0,1024); waves 4-7 (group 1) kv [1024,2048) for the SAME 128
// q-rows. Inner loop identical to v4 (96 VGPR there). NO min-waves clause in
// launch_bounds — R2's (512,4) forced a 128-reg cap -> spills (WRITE_SIZE
// 8->31.7MB). Natural regalloc ~96-112 <= 128 lets 2 blocks/CU co-reside =
// 4 waves/SIMD (the occupancy this grid can't otherwise reach).
// Post-loop: flash-combine of the two partial (m,l,O) states via LDS overlay.
__global__ void __launch_bounds__(512) attn_kernel(const u16* __restrict__ qk,
                                                   const u16* __restrict__ vT,
                                                   u16* __restrict__ attn_out) {
  // 64KB flat: K(g,buf) at (g*2+buf)*4096, V(g,buf) at 16384+(g*2+buf)*4096
  __shared__ u16 SM[32768];

  const int tid = threadIdx.x;
  const int wave = tid >> 6, lane = tid & 63;
  const int g = wave >> 2, gw = wave & 3;  // kv-group, wave-in-group
  const int q5 = lane & 31, hi = lane >> 5;
  const int qb = blockIdx.x, h = blockIdx.y, b = blockIdx.z;
  const size_t tok0 = (size_t)b * 2048;
  const float SCALE = 0.18033688011112042f;  // 0.125 * log2(e)

  u16* const Kg = SM + g * 2 * 4096;          // + buf*4096
  u16* const Vg = SM + 16384 + g * 2 * 4096;  // + buf*4096
  const int kvoff = g * 1024;

  // Q B-frags: lane q5 holds Q[q][ks*16 + hi*8 + j]
  const size_t qrow = tok0 + qb * 128 + gw * 32 + q5;
  const u16* qp = qk + qrow * 2048 + h * 64 + hi * 8;
  short8 qf[4];
#pragma unroll
  for (int ks = 0; ks < 4; ++ks) qf[ks] = *(const short8*)(qp + ks * 16);

  const u16* kbase = qk + tok0 * 2048 + 1024 + h * 64;  // + kv*2048
  const u16* vtb = vT + (size_t)h * 64 * 4096 + tok0;   // + d*4096 + kv

  // Static per-lane staging geometry (per group: 4 waves cover 8 row-groups)
  const int rowl = lane >> 3;
  const int k_srcoff = ((lane & 7) ^ rowl) * 8;  // K swizzle key = (row&7)

  float m_run = -1e30f, l_run = 0.f;
  f32x16 o0 = {}, o1 = {};

#define STAGE(kv0, buf)                                                        \
  {                                                                            \
    _Pragma("unroll") for (int c = 0; c < 2; ++c) {                            \
      int rw = c * 4 + gw;                                                     \
      int row = rw * 8 + rowl;                                                 \
      gload_lds16(kbase + (size_t)((kv0) + row) * 2048 + k_srcoff,             \
                  Kg + (buf) * 4096 + rw * 512);                               \
      int vso = (((lane & 7) ^ rowl ^ rw) * 8);  /* key = (d&7)^((d>>3)&7) */  \
      gload_lds16(vtb + (size_t)row * 4096 + (kv0) + vso,                      \
                  Vg + (buf) * 4096 + rw * 512);                               \
    }                                                                          \
  }

  STAGE(kvoff, 0);
  __syncthreads();

  for (int t = 0; t < 16; ++t) {
    const int cur = t & 1, nxt = cur ^ 1;
    if (t < 15) STAGE(kvoff + (t + 1) * 64, nxt);  // in flight across compute

    // ---- S^T = K . Q^T : 2 tiles (kv 0-31 / 32-63), 4 k-steps ----
    const u16* Kc = Kg + cur * 4096;
    f32x16 s0 = {}, s1 = {};
    __builtin_amdgcn_s_setprio(1);
#pragma unroll
    for (int ks = 0; ks < 4; ++ks) {
      int ch = ((ks * 2 + hi) ^ (q5 & 7)) * 8;
      short8 k0 = *(const short8*)(Kc + q5 * 64 + ch);
      short8 k1 = *(const short8*)(Kc + (32 + q5) * 64 + ch);
      s0 = MFMA32(k0, qf[ks], s0);
      s1 = MFMA32(k1, qf[ks], s1);
    }
    __builtin_amdgcn_s_setprio(0);

    // ---- online softmax, per-lane scalars (lane owns q = q5) ----
    float mt[8];
#pragma unroll
    for (int i = 0; i < 8; ++i)
      mt[i] = fmaxf(fmaxf(s0[i], s0[i + 8]), fmaxf(s1[i], s1[i + 8]));
    float pmax = fmaxf(fmaxf(fmaxf(mt[0], mt[1]), fmaxf(mt[2], mt[3])),
                       fmaxf(fmaxf(mt[4], mt[5]), fmaxf(mt[6], mt[7])));
    pmax = fmaxf(pmax, __shfl_xor(pmax, 32, 64));
    float mraw = pmax * SCALE;

    if (__any(mraw > m_run + 8.f)) {  // T13 defer-max, wave-uniform
      float mn = fmaxf(m_run, mraw);
      float alpha = fexp2(m_run - mn);
#pragma unroll
      for (int i = 0; i < 16; ++i) { o0[i] *= alpha; o1[i] *= alpha; }
      l_run *= alpha;
      m_run = mn;
    }

    float p0[16], p1[16];
    float rs = 0.f;
#pragma unroll
    for (int i = 0; i < 16; ++i) {
      p0[i] = fexp2(fmaf(s0[i], SCALE, -m_run));
      p1[i] = fexp2(fmaf(s1[i], SCALE, -m_run));
      rs += p0[i] + p1[i];
    }
    rs += __shfl_xor(rs, 32, 64);
    l_run += rs;

    // ---- P^T -> PV B-frags in-register (cvt_pk + permlane32_swap) ----
    u32 w0[4][2], w1[4][2];
#pragma unroll
    for (int a = 0; a < 4; ++a) {
      w0[a][0] = cvtpk_bf16(p0[4 * a], p0[4 * a + 1]);
      w0[a][1] = cvtpk_bf16(p0[4 * a + 2], p0[4 * a + 3]);
      w1[a][0] = cvtpk_bf16(p1[4 * a], p1[4 * a + 1]);
      w1[a][1] = cvtpk_bf16(p1[4 * a + 2], p1[4 * a + 3]);
    }
    short8 pb[4];
#pragma unroll
    for (int ks = 0; ks < 4; ++ks) {
      int e = ks & 1;
      u32 x0 = (ks < 2) ? w0[2 * e][0] : w1[2 * e][0];
      u32 y0 = (ks < 2) ? w0[2 * e + 1][0] : w1[2 * e + 1][0];
      u32 x1 = (ks < 2) ? w0[2 * e][1] : w1[2 * e][1];
      u32 y1 = (ks < 2) ? w0[2 * e + 1][1] : w1[2 * e + 1][1];
      asm("v_permlane32_swap_b32 %0, %1" : "+v"(x0), "+v"(y0));
      asm("v_permlane32_swap_b32 %0, %1" : "+v"(x1), "+v"(y1));
      u32x4 tt = {x0, x1, y0, y1};  // words j={0,1},{2,3},{4,5},{6,7}
      pb[ks] = __builtin_bit_cast(short8, tt);
    }

    // ---- O^T += V^T . P^T ----
    const u16* Vc = Vg + cur * 4096;
    __builtin_amdgcn_s_setprio(1);
#pragma unroll
    for (int ks = 0; ks < 4; ++ks) {
      int ch0 = ((ks * 2 + hi) ^ (q5 & 7) ^ ((q5 >> 3) & 7)) * 8;
      int ch1 = ch0 ^ (4 * 8);  // row 32+q5: (d>>3) flips bit 2
      short8 v0 = *(const short8*)(Vc + q5 * 64 + ch0);
      short8 v1 = *(const short8*)(Vc + (32 + q5) * 64 + ch1);
      o0 = MFMA32(v0, pb[ks], o0);
      o1 = MFMA32(v1, pb[ks], o1);
    }
    __builtin_amdgcn_s_setprio(0);

    __syncthreads();  // one barrier per tile: publishes K/V [nxt]
  }
#undef STAGE

  // ---- flash-combine of group 0/1 partials through LDS ----
  // overlay (K/V dead; last loop barrier ordered all reads):
  // per gw: M[64] | L[64] | O[32][64]  (2176 floats = 8704B; 4*8704 <= 64KB)
  float* sm = (float*)SM;
  float* base = sm + gw * 2176;
  if (g == 1) {
    base[lane] = m_run;
    base[64 + lane] = l_run;
#pragma unroll
    for (int i = 0; i < 16; ++i) {
      base[128 + i * 64 + lane] = o0[i];
      base[128 + (16 + i) * 64 + lane] = o1[i];
    }
  }
  __syncthreads();
  if (g == 0) {
    float m1 = base[lane], l1 = base[64 + lane];
    float M = fmaxf(m_run, m1);
    float wa = fexp2(m_run - M), wb = fexp2(m1 - M);
    float inv = 1.f / (wa * l_run + wb * l1);
    // epilogue: O^T[d][q], lane q5; d = (reg&3)+8*(reg>>2)+4*hi+32*dt
#pragma unroll
    for (int dt = 0; dt < 2; ++dt)
#pragma unroll
      for (int gq = 0; gq < 4; ++gq) {
        us4 st;
#pragma unroll
        for (int c2 = 0; c2 < 4; ++c2) {
          int i = 4 * gq + c2;
          float mine = (dt == 0) ? o0[i] : o1[i];
          float oth = base[128 + (dt * 16 + i) * 64 + lane];
          st[c2] = f2bf((wa * mine + wb * oth) * inv);
        }
        int col = h * 64 + dt * 32 + 8 * gq + 4 * hi;
        *(us4*)(attn_out + qrow * 1024 + col) = st;
      }
  }
}

// ================= launcher =================
extern "C" void kernel_launch(void* const* d_in, const int* in_sizes, int n_in,
                              void* d_out, int out_size, void* d_ws, size_t ws_size,
                              hipStream_t stream) {
  const float* x = (const float*)d_in[0];
  const float* Wqkv = (const float*)d_in[1];
  const float* Wproj = (const float*)d_in[2];
  const float* bproj = (const float*)d_in[3];
  float* out = (float*)d_out;

  char* ws = (char*)d_ws;
  u16* x_bf     = (u16*)(ws);                 //  8 MB  [4096,1024]
  u16* wqkv_bf  = (u16*)(ws + 8388608);       //  6 MB  [3072,1024]
  u16* wproj_bf = (u16*)(ws + 14680064);      //  2 MB  [1024,1024]
  u16* qk_bf    = (u16*)(ws + 16777216);      // 16 MB  [4096,2048] (Q|K)
  u16* vt_bf    = (u16*)(ws + 33554432);      //  8 MB  [1024,4096] V^T
  u16* attn_bf  = (u16*)(ws + 41943040);      //  8 MB  [4096,1024]

  cvt_all<<<8192, 256, 0, stream>>>(x, x_bf, Wqkv, wqkv_bf, Wproj, wproj_bf);

  fused_qkv_gemm<<<768, 256, 0, stream>>>(x_bf, wqkv_bf, qk_bf, vt_bf);

  dim3 g2(16, 16, 2);
  attn_kernel<<<g2, 512, 0, stream>>>(qk_bf, vt_bf, attn_bf);

  dim3 g3(32, 8);
  gemm_bt<1><<<g3, 256, 0, stream>>>(attn_bf, wproj_bf, nullptr, out, bproj,
                                     4096, 1024, 1024);
}

// Round 6
// 121.803 us; speedup vs baseline: 1.3100x; 1.0290x over previous
//
#include <hip/hip_runtime.h>

typedef unsigned short u16;
typedef unsigned int u32;
typedef __attribute__((ext_vector_type(8))) short short8;
typedef __attribute__((ext_vector_type(8))) __bf16 bf16x8;
typedef __attribute__((ext_vector_type(4))) float f32x4;
typedef __attribute__((ext_vector_type(16))) float f32x16;
typedef __attribute__((ext_vector_type(4))) unsigned short us4;
typedef __attribute__((ext_vector_type(4))) unsigned int u32x4;

#define DEVFN static __device__ __forceinline__

DEVFN u16 f2bf(float f) {
  u32 u = __float_as_uint(f);
  return (u16)((u + 0x7fffu + ((u >> 16) & 1u)) >> 16);  // RNE, finite inputs
}

#if __has_builtin(__builtin_amdgcn_exp2f)
DEVFN float fexp2(float x) { return __builtin_amdgcn_exp2f(x); }
#else
DEVFN float fexp2(float x) { return exp2f(x); }
#endif

// ---- MFMA wrappers: tolerant of short8-typed or bf16x8-typed builtins ----
template <typename T>
DEVFN auto mfma16_imp(T a, T b, f32x4 c, int)
    -> decltype(__builtin_amdgcn_mfma_f32_16x16x32_bf16(a, b, c, 0, 0, 0)) {
  return __builtin_amdgcn_mfma_f32_16x16x32_bf16(a, b, c, 0, 0, 0);
}
template <typename T>
DEVFN f32x4 mfma16_imp(T a, T b, f32x4 c, long) {
  return __builtin_amdgcn_mfma_f32_16x16x32_bf16(
      __builtin_bit_cast(bf16x8, a), __builtin_bit_cast(bf16x8, b), c, 0, 0, 0);
}
DEVFN f32x4 MFMA(short8 a, short8 b, f32x4 c) { return mfma16_imp(a, b, c, 0); }

template <typename T>
DEVFN auto mfma32_imp(T a, T b, f32x16 c, int)
    -> decltype(__builtin_amdgcn_mfma_f32_32x32x16_bf16(a, b, c, 0, 0, 0)) {
  return __builtin_amdgcn_mfma_f32_32x32x16_bf16(a, b, c, 0, 0, 0);
}
template <typename T>
DEVFN f32x16 mfma32_imp(T a, T b, f32x16 c, long) {
  return __builtin_amdgcn_mfma_f32_32x32x16_bf16(
      __builtin_bit_cast(bf16x8, a), __builtin_bit_cast(bf16x8, b), c, 0, 0, 0);
}
DEVFN f32x16 MFMA32(short8 a, short8 b, f32x16 c) { return mfma32_imp(a, b, c, 0); }

// ---- async global->LDS: dest = uniform base + lane*16 ----
DEVFN void gload_lds16(const u16* g, u16* l) {
  __builtin_amdgcn_global_load_lds(
      (__attribute__((address_space(1))) void*)g,
      (__attribute__((address_space(3))) void*)l, 16, 0, 0);
}

DEVFN u32 cvtpk_bf16(float lo, float hi) {
  u32 w;
  asm("v_cvt_pk_bf16_f32 %0, %1, %2" : "=v"(w) : "v"(lo), "v"(hi));
  return w;
}

// ================= fused f32 -> bf16 conversion (one launch) =============
__global__ void __launch_bounds__(256) cvt_all(
    const float* __restrict__ x, u16* __restrict__ xo,
    const float* __restrict__ w1, u16* __restrict__ w1o,
    const float* __restrict__ w2, u16* __restrict__ w2o) {
  int bid = blockIdx.x;
  const float* in;
  u16* out;
  int i;
  if (bid < 4096) {
    in = x; out = xo; i = bid * 256 + threadIdx.x;
  } else if (bid < 7168) {
    in = w1; out = w1o; i = (bid - 4096) * 256 + threadIdx.x;
  } else {
    in = w2; out = w2o; i = (bid - 7168) * 256 + threadIdx.x;
  }
  f32x4 v = ((const f32x4*)in)[i];
  us4 o;
  o[0] = f2bf(v[0]); o[1] = f2bf(v[1]); o[2] = f2bf(v[2]); o[3] = f2bf(v[3]);
  ((us4*)out)[i] = o;
}

// ====== GEMM tile body: C[bm:bm+128, bn:bn+BN] = A[M,K] @ B[N,K]^T ========
// BN = 128 (4 waves x 64x64, acc[4][4]) or 64 (4 waves x 64x32, acc[4][2]).
// BN=64 exists so small-N GEMMs can launch 2x the blocks: this 2-barrier
// structure needs >=2 blocks/CU for implicit overlap (R3/R4 evidence: at
// 1 block/CU the vmcnt(0)+barrier drain is fully exposed, ~2x slower).
template <int F32OUT, int BN>
DEVFN void gemm_tile(const u16* __restrict__ A, const u16* __restrict__ Bm,
                     u16* __restrict__ Cbf, float* __restrict__ Cf,
                     const float* __restrict__ bias, int N, int K, int bm,
                     int bn, u16* As, u16* Bs) {
  const int tid = threadIdx.x;
  const int wave = tid >> 6, lane = tid & 63;
  const int wr = (wave >> 1) * 64, wc = (wave & 1) * (BN / 2);
  const int srow = lane >> 2, scol = (lane & 3) * 8;
  const int fr = lane & 15, fk = (lane >> 4) * 8;
  const int NB = BN / 64;  // B-stage iters per wave
  const int NI = BN / 32;  // n-frags per wave

  f32x4 acc[4][NI] = {};

  for (int k0 = 0; k0 < K; k0 += 32) {
    __syncthreads();
#pragma unroll
    for (int t = 0; t < 2; ++t) {
      int rr = (wave * 2 + t) * 16 + srow;
      gload_lds16(A + (size_t)(bm + rr) * K + k0 + scol, As + (wave * 2 + t) * 512);
    }
#pragma unroll
    for (int t = 0; t < NB; ++t) {
      int rr = (wave * NB + t) * 16 + srow;
      gload_lds16(Bm + (size_t)(bn + rr) * K + k0 + scol, Bs + (wave * NB + t) * 512);
    }
    __syncthreads();
    short8 af[4], bf[NI];
#pragma unroll
    for (int i = 0; i < 4; ++i)
      af[i] = *(const short8*)(As + (wr + i * 16 + fr) * 32 + fk);
#pragma unroll
    for (int i = 0; i < NI; ++i)
      bf[i] = *(const short8*)(Bs + (wc + i * 16 + fr) * 32 + fk);
#pragma unroll
    for (int mi = 0; mi < 4; ++mi)
#pragma unroll
      for (int ni = 0; ni < NI; ++ni)
        acc[mi][ni] = MFMA(af[mi], bf[ni], acc[mi][ni]);
  }

  const int orow = (lane >> 4) * 4, ocol = lane & 15;
#pragma unroll
  for (int mi = 0; mi < 4; ++mi)
#pragma unroll
    for (int ni = 0; ni < NI; ++ni)
#pragma unroll
      for (int r = 0; r < 4; ++r) {
        size_t row = (size_t)(bm + wr + mi * 16 + orow + r);
        size_t col = (size_t)(bn + wc + ni * 16 + ocol);
        if (F32OUT)
          Cf[row * N + col] = acc[mi][ni][r] + bias[col];
        else
          Cbf[row * N + col] = f2bf(acc[mi][ni][r]);
      }
}

// ====== output projection: 128x64 tiles -> 512 blocks (2 blocks/CU) ======
__global__ void __launch_bounds__(256) gemm_proj(
    const u16* __restrict__ A, const u16* __restrict__ Bm,
    float* __restrict__ Cf, const float* __restrict__ bias, int M, int N,
    int K) {
  __shared__ u16 As[128 * 32];
  __shared__ u16 Bs[64 * 32];
  gemm_tile<1, 64>(A, Bm, nullptr, Cf, bias, N, K, blockIdx.x * 128,
                   blockIdx.y * 64, As, Bs);
}

// ====== fused projection: QK = x @ Wqk^T  and  V^T = Wv @ x^T =============
// One 768-block launch so both sub-GEMMs are co-resident (3 blocks/CU).
__global__ void __launch_bounds__(256) fused_qkv_gemm(
    const u16* __restrict__ x, const u16* __restrict__ wqkv,
    u16* __restrict__ qk, u16* __restrict__ vt) {
  __shared__ u16 As[128 * 32];
  __shared__ u16 Bs[128 * 32];
  int bid = blockIdx.x;
  if (bid < 512) {
    gemm_tile<0, 128>(x, wqkv, qk, nullptr, nullptr, 2048, 1024,
                      (bid & 31) * 128, (bid >> 5) * 128, As, Bs);
  } else {
    int j = bid - 512;
    gemm_tile<0, 128>(wqkv + (size_t)2048 * 1024, x, vt, nullptr, nullptr,
                      4096, 1024, (j & 7) * 128, (j >> 3) * 128, As, Bs);
  }
}

// ================= Flash attention v5: v4 + in-block KV-split x2 ==========
// qk: [4096, 2048] bf16 (Q|K). vT: [1024, 4096] bf16 (vfeat, token).
// Grid (16 qblk, 16 heads, 2 batch), 512 thr (8 waves). Waves 0-3 (group 0)
// process kv [0,1024); waves 4-7 (group 1) kv [1024,2048) for the SAME 128
// q-rows. NO min-waves clause in launch_bounds (R2: forced reg cap -> spill).
// Compiler lands at 64 VGPR -> 2 blocks/CU co-reside (R5: 55.5us, occ 33%).
// Post-loop: flash-combine of the two partial (m,l,O) states via LDS overlay.
__global__ void __launch_bounds__(512) attn_kernel(const u16* __restrict__ qk,
                                                   const u16* __restrict__ vT,
                                                   u16* __restrict__ attn_out) {
  // 64KB flat: K(g,buf) at (g*2+buf)*4096, V(g,buf) at 16384+(g*2+buf)*4096
  __shared__ u16 SM[32768];

  const int tid = threadIdx.x;
  const int wave = tid >> 6, lane = tid & 63;
  const int g = wave >> 2, gw = wave & 3;  // kv-group, wave-in-group
  const int q5 = lane & 31, hi = lane >> 5;
  const int qb = blockIdx.x, h = blockIdx.y, b = blockIdx.z;
  const size_t tok0 = (size_t)b * 2048;
  const float SCALE = 0.18033688011112042f;  // 0.125 * log2(e)

  u16* const Kg = SM + g * 2 * 4096;          // + buf*4096
  u16* const Vg = SM + 16384 + g * 2 * 4096;  // + buf*4096
  const int kvoff = g * 1024;

  // Q B-frags: lane q5 holds Q[q][ks*16 + hi*8 + j]
  const size_t qrow = tok0 + qb * 128 + gw * 32 + q5;
  const u16* qp = qk + qrow * 2048 + h * 64 + hi * 8;
  short8 qf[4];
#pragma unroll
  for (int ks = 0; ks < 4; ++ks) qf[ks] = *(const short8*)(qp + ks * 16);

  const u16* kbase = qk + tok0 * 2048 + 1024 + h * 64;  // + kv*2048
  const u16* vtb = vT + (size_t)h * 64 * 4096 + tok0;   // + d*4096 + kv

  // Static per-lane staging geometry (per group: 4 waves cover 8 row-groups)
  const int rowl = lane >> 3;
  const int k_srcoff = ((lane & 7) ^ rowl) * 8;  // K swizzle key = (row&7)

  float m_run = -1e30f, l_run = 0.f;
  f32x16 o0 = {}, o1 = {};

#define STAGE(kv0, buf)                                                        \
  {                                                                            \
    _Pragma("unroll") for (int c = 0; c < 2; ++c) {                            \
      int rw = c * 4 + gw;                                                     \
      int row = rw * 8 + rowl;                                                 \
      gload_lds16(kbase + (size_t)((kv0) + row) * 2048 + k_srcoff,             \
                  Kg + (buf) * 4096 + rw * 512);                               \
      int vso = (((lane & 7) ^ rowl ^ rw) * 8);  /* key = (d&7)^((d>>3)&7) */  \
      gload_lds16(vtb + (size_t)row * 4096 + (kv0) + vso,                      \
                  Vg + (buf) * 4096 + rw * 512);                               \
    }                                                                          \
  }

  STAGE(kvoff, 0);
  __syncthreads();

  for (int t = 0; t < 16; ++t) {
    const int cur = t & 1, nxt = cur ^ 1;
    if (t < 15) STAGE(kvoff + (t + 1) * 64, nxt);  // in flight across compute

    // ---- S^T = K . Q^T : 2 tiles (kv 0-31 / 32-63), 4 k-steps ----
    const u16* Kc = Kg + cur * 4096;
    f32x16 s0 = {}, s1 = {};
    __builtin_amdgcn_s_setprio(1);
#pragma unroll
    for (int ks = 0; ks < 4; ++ks) {
      int ch = ((ks * 2 + hi) ^ (q5 & 7)) * 8;
      short8 k0 = *(const short8*)(Kc + q5 * 64 + ch);
      short8 k1 = *(const short8*)(Kc + (32 + q5) * 64 + ch);
      s0 = MFMA32(k0, qf[ks], s0);
      s1 = MFMA32(k1, qf[ks], s1);
    }
    __builtin_amdgcn_s_setprio(0);

    // ---- online softmax, per-lane scalars (lane owns q = q5) ----
    float mt[8];
#pragma unroll
    for (int i = 0; i < 8; ++i)
      mt[i] = fmaxf(fmaxf(s0[i], s0[i + 8]), fmaxf(s1[i], s1[i + 8]));
    float pmax = fmaxf(fmaxf(fmaxf(mt[0], mt[1]), fmaxf(mt[2], mt[3])),
                       fmaxf(fmaxf(mt[4], mt[5]), fmaxf(mt[6], mt[7])));
    pmax = fmaxf(pmax, __shfl_xor(pmax, 32, 64));
    float mraw = pmax * SCALE;

    if (__any(mraw > m_run + 8.f)) {  // T13 defer-max, wave-uniform
      float mn = fmaxf(m_run, mraw);
      float alpha = fexp2(m_run - mn);
#pragma unroll
      for (int i = 0; i < 16; ++i) { o0[i] *= alpha; o1[i] *= alpha; }
      l_run *= alpha;
      m_run = mn;
    }

    float p0[16], p1[16];
    float rs = 0.f;
#pragma unroll
    for (int i = 0; i < 16; ++i) {
      p0[i] = fexp2(fmaf(s0[i], SCALE, -m_run));
      p1[i] = fexp2(fmaf(s1[i], SCALE, -m_run));
      rs += p0[i] + p1[i];
    }
    rs += __shfl_xor(rs, 32, 64);
    l_run += rs;

    // ---- P^T -> PV B-frags in-register (cvt_pk + permlane32_swap) ----
    u32 w0[4][2], w1[4][2];
#pragma unroll
    for (int a = 0; a < 4; ++a) {
      w0[a][0] = cvtpk_bf16(p0[4 * a], p0[4 * a + 1]);
      w0[a][1] = cvtpk_bf16(p0[4 * a + 2], p0[4 * a + 3]);
      w1[a][0] = cvtpk_bf16(p1[4 * a], p1[4 * a + 1]);
      w1[a][1] = cvtpk_bf16(p1[4 * a + 2], p1[4 * a + 3]);
    }
    short8 pb[4];
#pragma unroll
    for (int ks = 0; ks < 4; ++ks) {
      int e = ks & 1;
      u32 x0 = (ks < 2) ? w0[2 * e][0] : w1[2 * e][0];
      u32 y0 = (ks < 2) ? w0[2 * e + 1][0] : w1[2 * e + 1][0];
      u32 x1 = (ks < 2) ? w0[2 * e][1] : w1[2 * e][1];
      u32 y1 = (ks < 2) ? w0[2 * e + 1][1] : w1[2 * e + 1][1];
      asm("v_permlane32_swap_b32 %0, %1" : "+v"(x0), "+v"(y0));
      asm("v_permlane32_swap_b32 %0, %1" : "+v"(x1), "+v"(y1));
      u32x4 tt = {x0, x1, y0, y1};  // words j={0,1},{2,3},{4,5},{6,7}
      pb[ks] = __builtin_bit_cast(short8, tt);
    }

    // ---- O^T += V^T . P^T ----
    const u16* Vc = Vg + cur * 4096;
    __builtin_amdgcn_s_setprio(1);
#pragma unroll
    for (int ks = 0; ks < 4; ++ks) {
      int ch0 = ((ks * 2 + hi) ^ (q5 & 7) ^ ((q5 >> 3) & 7)) * 8;
      int ch1 = ch0 ^ (4 * 8);  // row 32+q5: (d>>3) flips bit 2
      short8 v0 = *(const short8*)(Vc + q5 * 64 + ch0);
      short8 v1 = *(const short8*)(Vc + (32 + q5) * 64 + ch1);
      o0 = MFMA32(v0, pb[ks], o0);
      o1 = MFMA32(v1, pb[ks], o1);
    }
    __builtin_amdgcn_s_setprio(0);

    __syncthreads();  // one barrier per tile: publishes K/V [nxt]
  }
#undef STAGE

  // ---- flash-combine of group 0/1 partials through LDS ----
  // overlay (K/V dead; last loop barrier ordered all reads):
  // per gw: M[64] | L[64] | O[32][64]  (2176 floats = 8704B; 4*8704 <= 64KB)
  float* sm = (float*)SM;
  float* base = sm + gw * 2176;
  if (g == 1) {
    base[lane] = m_run;
    base[64 + lane] = l_run;
#pragma unroll
    for (int i = 0; i < 16; ++i) {
      base[128 + i * 64 + lane] = o0[i];
      base[128 + (16 + i) * 64 + lane] = o1[i];
    }
  }
  __syncthreads();
  if (g == 0) {
    float m1 = base[lane], l1 = base[64 + lane];
    float M = fmaxf(m_run, m1);
    float wa = fexp2(m_run - M), wb = fexp2(m1 - M);
    float inv = 1.f / (wa * l_run + wb * l1);
    // epilogue: O^T[d][q], lane q5; d = (reg&3)+8*(reg>>2)+4*hi+32*dt
#pragma unroll
    for (int dt = 0; dt < 2; ++dt)
#pragma unroll
      for (int gq = 0; gq < 4; ++gq) {
        us4 st;
#pragma unroll
        for (int c2 = 0; c2 < 4; ++c2) {
          int i = 4 * gq + c2;
          float mine = (dt == 0) ? o0[i] : o1[i];
          float oth = base[128 + (dt * 16 + i) * 64 + lane];
          st[c2] = f2bf((wa * mine + wb * oth) * inv);
        }
        int col = h * 64 + dt * 32 + 8 * gq + 4 * hi;
        *(us4*)(attn_out + qrow * 1024 + col) = st;
      }
  }
}

// ================= launcher =================
extern "C" void kernel_launch(void* const* d_in, const int* in_sizes, int n_in,
                              void* d_out, int out_size, void* d_ws, size_t ws_size,
                              hipStream_t stream) {
  const float* x = (const float*)d_in[0];
  const float* Wqkv = (const float*)d_in[1];
  const float* Wproj = (const float*)d_in[2];
  const float* bproj = (const float*)d_in[3];
  float* out = (float*)d_out;

  char* ws = (char*)d_ws;
  u16* x_bf     = (u16*)(ws);                 //  8 MB  [4096,1024]
  u16* wqkv_bf  = (u16*)(ws + 8388608);       //  6 MB  [3072,1024]
  u16* wproj_bf = (u16*)(ws + 14680064);      //  2 MB  [1024,1024]
  u16* qk_bf    = (u16*)(ws + 16777216);      // 16 MB  [4096,2048] (Q|K)
  u16* vt_bf    = (u16*)(ws + 33554432);      //  8 MB  [1024,4096] V^T
  u16* attn_bf  = (u16*)(ws + 41943040);      //  8 MB  [4096,1024]

  cvt_all<<<8192, 256, 0, stream>>>(x, x_bf, Wqkv, wqkv_bf, Wproj, wproj_bf);

  fused_qkv_gemm<<<768, 256, 0, stream>>>(x_bf, wqkv_bf, qk_bf, vt_bf);

  dim3 g2(16, 16, 2);
  attn_kernel<<<g2, 512, 0, stream>>>(qk_bf, vt_bf, attn_bf);

  dim3 g3(32, 16);  // 128x64 tiles -> 512 blocks (2/CU)
  gemm_proj<<<g3, 256, 0, stream>>>(attn_bf, wproj_bf, out, bproj,
                                    4096, 1024, 1024);
}